// Round 2
// baseline (208.416 us; speedup 1.0000x reference)
//
#include <hip/hip_runtime.h>

typedef __attribute__((ext_vector_type(8))) short bf16x8;
typedef __attribute__((ext_vector_type(4))) float f32x4;

// ---------------------------------------------------------------------------
// Posit(8,1) round-to-nearest quantization, bit-exact vs the jnp reference.
// ---------------------------------------------------------------------------
__device__ __forceinline__ float posit_q(float x) {
  float ax = fabsf(x);
  ax = fmaxf(ax, 0x1p-12f);
  ax = fminf(ax, 0x1p12f);
  int s = (int)(__float_as_uint(ax) >> 23) - 127;   // floor(log2(ax)), exact
  int k = s >> 1;                                   // floor(s/2)
  int rlen = (k >= 0) ? (k + 2) : (1 - k);
  int fbits = 6 - rlen;
  fbits = fbits < 0 ? 0 : fbits;
  float m = ax * __uint_as_float((unsigned)(127 - s) << 23);  // [1,2)
  float fs = (float)(1 << fbits);
  float inv_fs = __uint_as_float((unsigned)(127 - fbits) << 23);
  float mq = rintf(m * fs) * inv_fs;                // round-half-even = jnp.round
  if (mq >= 2.0f) { s += 1; mq = 1.0f; }            // mantissa carry
  float y = mq * __uint_as_float((unsigned)(127 + s) << 23);
  y = fminf(y, 0x1p12f);
  y = copysignf(y, x);
  return (x == 0.0f) ? 0.0f : y;
}

__device__ __forceinline__ ushort4 quant4_bf16(float4 v) {
  ushort4 o;
  o.x = (ushort)(__float_as_uint(posit_q(v.x)) >> 16);
  o.y = (ushort)(__float_as_uint(posit_q(v.y)) >> 16);
  o.z = (ushort)(__float_as_uint(posit_q(v.z)) >> 16);
  o.w = (ushort)(__float_as_uint(posit_q(v.w)) >> 16);
  return o;
}

__global__ void posit_quant_all(const float* __restrict__ x,
                                const float* __restrict__ w,
                                const float* __restrict__ b,
                                ushort* __restrict__ Xq,
                                ushort* __restrict__ Wq,
                                float* __restrict__ bq,
                                int nx4, int nw4, int nb4) {
  int i = blockIdx.x * blockDim.x + threadIdx.x;
  if (i < nx4) {
    ((ushort4*)Xq)[i] = quant4_bf16(((const float4*)x)[i]);
  } else if (i < nx4 + nw4) {
    int j = i - nx4;
    ((ushort4*)Wq)[j] = quant4_bf16(((const float4*)w)[j]);
  } else if (i < nx4 + nw4 + nb4) {
    int j = i - nx4 - nw4;
    float4 v = ((const float4*)b)[j];
    float4 o;
    o.x = posit_q(v.x); o.y = posit_q(v.y);
    o.z = posit_q(v.z); o.w = posit_q(v.w);
    ((float4*)bq)[j] = o;
  }
}

// ---------------------------------------------------------------------------
// R7: m201-style derived-waits 8-phase schedule. 256x256 tile, BK=64,
// 512 thr = 8 waves (2M x 4N), fixed-parity dbuf (buf0=even K-tiles,
// buf1=odd), 128 KiB LDS, grid 8x32 = 256 = 1 block/CU.
//
// Iteration u = K-tiles a=2u (buf0, phases 1-4) and b=2u+1 (buf1, 5-8).
// Quadrant order per tile: (Alo,Blo)(Ahi,Blo)(Ahi,Bhi)(Alo,Bhi); fa_lo/fa_hi
// persist in regs so ds_reads/phase = 12/8/4/0. Stage units are 128-row
// half-tiles (A-lo = rounds {0,2}, A-hi = {1,3}; B-lo = rows 0-31 of each
// 64-row round, B-hi = rows 32-63), 2 gl_lds per wave per unit.
// Stage slots (all in the phase after the region's last ds_read):
//   ph1: Alo+Bhi(2u+1)->buf1   ph3: Blo(2u+2)->buf0   ph4: Ahi(2u+2)->buf0
//   ph5: Alo+Bhi(2u+2)->buf0   ph7: Blo(2u+3)->buf1   ph8: Ahi(2u+3)->buf1
// Counted waits, never 0 mid-loop (T4):
//   ph4-end vmcnt(4): leaves {ph3,ph4}; guarantees prev-ph7/ph8 + this-ph1
//     landed  -> all of tile b readable in ph5-8.
//   ph8-end vmcnt(4): leaves {ph7,ph8}; guarantees ph3/ph4/ph5 landed
//     -> all of tile 2u+2 readable next iteration.
// Last iteration: stages guarded off; ph4 wait becomes vmcnt(0) (covers ph1).
// Swizzle (0-conflict, R3/R5-proven): 16B chunk q of row r at slot q^(r&7),
// pre-applied to the GLOBAL source so LDS dests stay lane-linear.
// ---------------------------------------------------------------------------
__device__ __forceinline__ void gl_lds16(const ushort* g, ushort* l) {
  __builtin_amdgcn_global_load_lds(
      (const __attribute__((address_space(1))) void*)g,
      (__attribute__((address_space(3))) void*)l,
      16, 0, 0);
}

#define BAR() __builtin_amdgcn_s_barrier()
#define LGKM0() asm volatile("s_waitcnt lgkmcnt(0)" ::: "memory")

__global__ __launch_bounds__(512, 2) void posit_gemm(
    const ushort* __restrict__ A, const ushort* __restrict__ B,
    const float* __restrict__ bq, float* __restrict__ C,
    int M, int N, int K) {
  __shared__ ushort lds[65536];   // A0[16K] A1[16K] B0[16K] B1[16K] elems

  const int tid = threadIdx.x;
  const int wave = tid >> 6;
  const int lane = tid & 63;
  const int wm = wave >> 2;         // 0..1 : 128-row slab
  const int wn = wave & 3;          // 0..3 : 64-col slab
  const int m0 = blockIdx.y << 8;
  const int n0 = blockIdx.x << 8;

  ushort* const A0 = lds;
  ushort* const A1 = lds + 16384;
  ushort* const B0 = lds + 32768;
  ushort* const B1 = lds + 49152;

  // staging thread geometry: within an 8-row slab, lane covers row l8,
  // chunk lane&7, source pre-swizzled by row&7 == l8 (slabs 8-row aligned).
  const int l8 = lane >> 3;
  const int scol = ((lane & 7) ^ l8) << 3;
  const ushort* Ag = A + (size_t)(m0 + l8) * K + scol;
  const ushort* Bg = B + (size_t)(n0 + l8) * K + scol;

  // per-wave slab bases (2 issues per unit), e = wave*2 + q
  const int e0 = wave << 1, e1 = e0 + 1;
  const int rAlo0 = (e0 << 3) + ((e0 >> 3) << 6);
  const int rAlo1 = (e1 << 3) + ((e1 >> 3) << 6);
  const int rAhi0 = rAlo0 + 64, rAhi1 = rAlo1 + 64;
  const int rBlo0 = ((e0 >> 2) << 6) + ((e0 & 3) << 3);
  const int rBlo1 = ((e1 >> 2) << 6) + ((e1 & 3) << 3);
  const int rBhi0 = rBlo0 + 32, rBhi1 = rBlo1 + 32;

#define ST_A(buf, r0, r1, kt) {                                   \
    gl_lds16(Ag + (size_t)(r0) * K + (kt), (buf) + ((r0) << 6));  \
    gl_lds16(Ag + (size_t)(r1) * K + (kt), (buf) + ((r1) << 6)); }
#define ST_B(buf, r0, r1, kt) {                                   \
    gl_lds16(Bg + (size_t)(r0) * K + (kt), (buf) + ((r0) << 6));  \
    gl_lds16(Bg + (size_t)(r1) * K + (kt), (buf) + ((r1) << 6)); }

  // fragment read geometry
  const int fr = lane & 15;
  const int t4 = lane >> 4;
  const int swz = fr & 7;
  const int c0 = (t4 ^ swz) << 3;
  const int c1 = ((4 + t4) ^ swz) << 3;
  const int arl = ((wm << 7) + fr) << 6;   // + i<<10 ; fa_hi adds 4096
  const int brl = ((wn << 6) + fr) << 6;   // + j<<10

#define RD_A(dst, base, hi)                                            \
  _Pragma("unroll") for (int i = 0; i < 4; i++) {                      \
    dst[i][0] = *(const bf16x8*)((base) + arl + (hi) + (i << 10) + c0);\
    dst[i][1] = *(const bf16x8*)((base) + arl + (hi) + (i << 10) + c1); }
#define RD_B(dst, base, jo)                                            \
  _Pragma("unroll") for (int j = 0; j < 2; j++) {                      \
    dst[j][0] = *(const bf16x8*)((base) + brl + (((jo) + j) << 10) + c0);\
    dst[j][1] = *(const bf16x8*)((base) + brl + (((jo) + j) << 10) + c1); }

#define MFMA_Q(AF, BF, I0, J0)                                         \
  __builtin_amdgcn_s_setprio(1);                                       \
  _Pragma("unroll") for (int kk = 0; kk < 2; kk++)                     \
    _Pragma("unroll") for (int i = 0; i < 4; i++)                      \
      _Pragma("unroll") for (int j = 0; j < 2; j++)                    \
        acc[(I0) + i][(J0) + j] = __builtin_amdgcn_mfma_f32_16x16x32_bf16( \
            AF[i][kk], BF[j][kk], acc[(I0) + i][(J0) + j], 0, 0, 0);   \
  __builtin_amdgcn_s_setprio(0);

  f32x4 acc[8][4];
#pragma unroll
  for (int i = 0; i < 8; i++)
#pragma unroll
    for (int j = 0; j < 4; j++) acc[i][j] = (f32x4){0.f, 0.f, 0.f, 0.f};

  // ---- prologue: tile0 complete -> buf0; tile1 partial (Blo,Ahi) -> buf1.
  ST_A(A0, rAlo0, rAlo1, 0);
  ST_B(B0, rBlo0, rBlo1, 0);
  ST_A(A0, rAhi0, rAhi1, 0);
  ST_B(B0, rBhi0, rBhi1, 0);
  ST_B(B1, rBlo0, rBlo1, 64);
  ST_A(A1, rAhi0, rAhi1, 64);
  asm volatile("s_waitcnt vmcnt(4)" ::: "memory");   // tile0 landed
  BAR();

  const int T = K >> 6;
  const int U = T >> 1;

#pragma unroll 1
  for (int u = 0; u < U; ++u) {
    const int ktb = (u << 7) + 64;    // tile 2u+1
    const int kt2 = (u << 7) + 128;   // tile 2u+2
    const int kt3 = (u << 7) + 192;   // tile 2u+3
    const bool stg = (u + 1 < U);

    bf16x8 falo[4][2], fahi[4][2], fbl[2][2], fbh[2][2];

    // ---- ph1: q1(a) = (Alo,Blo); stage Alo+Bhi(2u+1) -> buf1
    RD_A(falo, A0, 0);
    RD_B(fbl, B0, 0);
    ST_A(A1, rAlo0, rAlo1, ktb);
    ST_B(B1, rBhi0, rBhi1, ktb);
    BAR(); LGKM0();
    MFMA_Q(falo, fbl, 0, 0);
    BAR();

    // ---- ph2: q2(a) = (Ahi,Blo)
    RD_A(fahi, A0, 4096);
    BAR(); LGKM0();
    MFMA_Q(fahi, fbl, 4, 0);
    BAR();

    // ---- ph3: q3(a) = (Ahi,Bhi); stage Blo(2u+2) -> buf0
    RD_B(fbh, B0, 2);
    if (stg) ST_B(B0, rBlo0, rBlo1, kt2);
    BAR(); LGKM0();
    MFMA_Q(fahi, fbh, 4, 2);
    BAR();

    // ---- ph4: q4(a) = (Alo,Bhi); stage Ahi(2u+2) -> buf0; W4
    if (stg) ST_A(A0, rAhi0, rAhi1, kt2);
    BAR();
    MFMA_Q(falo, fbh, 0, 2);
    if (stg) { asm volatile("s_waitcnt vmcnt(4)" ::: "memory"); }
    else     { asm volatile("s_waitcnt vmcnt(0)" ::: "memory"); }
    BAR();

    // ---- ph5: q1(b); stage Alo+Bhi(2u+2) -> buf0
    RD_A(falo, A1, 0);
    RD_B(fbl, B1, 0);
    if (stg) {
      ST_A(A0, rAlo0, rAlo1, kt2);
      ST_B(B0, rBhi0, rBhi1, kt2);
    }
    BAR(); LGKM0();
    MFMA_Q(falo, fbl, 0, 0);
    BAR();

    // ---- ph6: q2(b)
    RD_A(fahi, A1, 4096);
    BAR(); LGKM0();
    MFMA_Q(fahi, fbl, 4, 0);
    BAR();

    // ---- ph7: q3(b); stage Blo(2u+3) -> buf1
    RD_B(fbh, B1, 2);
    if (stg) ST_B(B1, rBlo0, rBlo1, kt3);
    BAR(); LGKM0();
    MFMA_Q(fahi, fbh, 4, 2);
    BAR();

    // ---- ph8: q4(b); stage Ahi(2u+3) -> buf1; W8
    if (stg) ST_A(A1, rAhi0, rAhi1, kt3);
    BAR();
    MFMA_Q(falo, fbh, 0, 2);
    if (stg) { asm volatile("s_waitcnt vmcnt(4)" ::: "memory"); }
    BAR();
  }

  // Epilogue: C/D layout col = lane&15, row = (lane>>4)*4 + reg. Fuse bias.
  const int row0 = m0 + (wm << 7) + (t4 << 2);
  const int col0 = n0 + (wn << 6) + fr;
#pragma unroll
  for (int j = 0; j < 4; j++) {
    const int col = col0 + (j << 4);
    const float bv = bq[col];
#pragma unroll
    for (int i = 0; i < 8; i++) {
      const int row = row0 + (i << 4);
#pragma unroll
      for (int r = 0; r < 4; r++)
        C[(size_t)(row + r) * N + col] = acc[i][j][r] + bv;
    }
  }
}

extern "C" void kernel_launch(void* const* d_in, const int* in_sizes, int n_in,
                              void* d_out, int out_size, void* d_ws, size_t ws_size,
                              hipStream_t stream) {
  const float* x = (const float*)d_in[0];
  const float* w = (const float*)d_in[1];
  const float* bias = (const float*)d_in[2];
  float* out = (float*)d_out;

  const int out_f = in_sizes[2];                 // 2048
  const int in_f = in_sizes[1] / out_f;          // 2048
  const int m = in_sizes[0] / in_f;              // 8192
  const int k = in_f;

  // workspace layout: Xq bf16 | Wq bf16 | bq fp32
  ushort* Xq = (ushort*)d_ws;
  ushort* Wq = Xq + (size_t)m * k;
  float* bquant = (float*)(Wq + (size_t)out_f * k);

  const int nx4 = in_sizes[0] / 4;
  const int nw4 = in_sizes[1] / 4;
  const int nb4 = in_sizes[2] / 4;
  const int total4 = nx4 + nw4 + nb4;
  posit_quant_all<<<(total4 + 255) / 256, 256, 0, stream>>>(
      x, w, bias, Xq, Wq, bquant, nx4, nw4, nb4);

  dim3 grid(out_f / 256, m / 256);
  posit_gemm<<<grid, 512, 0, stream>>>(Xq, Wq, bquant, out, m, out_f, k);
}

// Round 3
// 189.796 us; speedup vs baseline: 1.0981x; 1.0981x over previous
//
#include <hip/hip_runtime.h>

typedef __attribute__((ext_vector_type(8))) short bf16x8;
typedef __attribute__((ext_vector_type(4))) float f32x4;

// ---------------------------------------------------------------------------
// Posit(8,1) round-to-nearest posit quantization, bit-exact vs jnp reference.
// two_es=2, npat=6, maxpos=2^12, minpos=2^-12. Result has <=4 fraction bits ->
// exactly representable in bf16 (and fp32).
// ---------------------------------------------------------------------------
__device__ __forceinline__ float posit_q(float x) {
  float ax = fabsf(x);
  ax = fmaxf(ax, 0x1p-12f);
  ax = fminf(ax, 0x1p12f);
  int s = (int)(__float_as_uint(ax) >> 23) - 127;   // floor(log2(ax)), exact
  int k = s >> 1;                                   // floor(s/2)
  int rlen = (k >= 0) ? (k + 2) : (1 - k);
  int fbits = 6 - rlen;
  fbits = fbits < 0 ? 0 : fbits;
  float m = ax * __uint_as_float((unsigned)(127 - s) << 23);  // [1,2)
  float fs = (float)(1 << fbits);
  float inv_fs = __uint_as_float((unsigned)(127 - fbits) << 23);
  float mq = rintf(m * fs) * inv_fs;                // round-half-even = jnp.round
  if (mq >= 2.0f) { s += 1; mq = 1.0f; }            // mantissa carry
  float y = mq * __uint_as_float((unsigned)(127 + s) << 23);
  y = fminf(y, 0x1p12f);
  y = copysignf(y, x);
  return (x == 0.0f) ? 0.0f : y;
}

__device__ __forceinline__ ushort4 quant4_bf16(float4 v) {
  ushort4 o;
  o.x = (ushort)(__float_as_uint(posit_q(v.x)) >> 16);
  o.y = (ushort)(__float_as_uint(posit_q(v.y)) >> 16);
  o.z = (ushort)(__float_as_uint(posit_q(v.z)) >> 16);
  o.w = (ushort)(__float_as_uint(posit_q(v.w)) >> 16);
  return o;
}

// One merged quantize kernel: x -> bf16, w -> bf16, bias -> fp32.
__global__ void posit_quant_all(const float* __restrict__ x,
                                const float* __restrict__ w,
                                const float* __restrict__ b,
                                ushort* __restrict__ Xq,
                                ushort* __restrict__ Wq,
                                float* __restrict__ bq,
                                int nx4, int nw4, int nb4) {
  int i = blockIdx.x * blockDim.x + threadIdx.x;
  if (i < nx4) {
    ((ushort4*)Xq)[i] = quant4_bf16(((const float4*)x)[i]);
  } else if (i < nx4 + nw4) {
    int j = i - nx4;
    ((ushort4*)Wq)[j] = quant4_bf16(((const float4*)w)[j]);
  } else if (i < nx4 + nw4 + nb4) {
    int j = i - nx4 - nw4;
    float4 v = ((const float4*)b)[j];
    float4 o;
    o.x = posit_q(v.x); o.y = posit_q(v.y);
    o.z = posit_q(v.z); o.w = posit_q(v.w);
    ((float4*)bq)[j] = o;
  }
}

// ---------------------------------------------------------------------------
// R8 = R5 (256x128 tile, 512 thr / 8 waves 4x2, BK=64, 2 blocks/CU) with ONE
// structural change: A is double-buffered (32 KB x2) + B single (16 KB) =
// 80 KB LDS = exactly 2 blocks/CU, and the per-step __syncthreads vmcnt(0)
// drain is replaced by raw s_barrier + counted s_waitcnt.
//
// Per step t: issue B(t) [2 loads], then A(t+1)->other buffer [4 loads], then
// vmcnt(4). FIFO retirement: outstanding = A(t)[4, oldest; issued last step,
// ~2500 cyc ago -> latency hidden] + B(t)[2] + A(t+1)[4, newest]; vmcnt(4)
// retires A(t)+B(t), leaves A(t+1) in flight across the barrier (T4: never
// drain to 0 mid-loop). Only B's L2 latency (~200-500 cyc) stays exposed,
// and the co-resident block's waves hide it (cross-block overlap, as in R5).
// WAR: staged A-buffer was last read in step t-1, completed before that
// step's end barrier; B(t) overwrite of B(t-1) likewise. Final step drains
// vmcnt(0) once (vmcnt(4) there would leave B un-retired - FIFO).
//
// Swizzle (R3/R5-proven, 0 conflicts): 16B k-chunk at position p of row r
// stored at p ^ (r&7); pre-applied to the GLOBAL source address so LDS dests
// stay lane-contiguous as global_load_lds requires.
// ---------------------------------------------------------------------------
__device__ __forceinline__ void gl_lds16(const ushort* g, ushort* l) {
  __builtin_amdgcn_global_load_lds(
      (const __attribute__((address_space(1))) void*)g,
      (__attribute__((address_space(3))) void*)l,
      16, 0, 0);
}

__global__ __launch_bounds__(512, 4) void posit_gemm(
    const ushort* __restrict__ A, const ushort* __restrict__ B,
    const float* __restrict__ bq, float* __restrict__ C,
    int M, int N, int K) {
  __shared__ ushort lds[40960];     // 80 KB: A dbuf [0,32768) , B [32768,40960)

  const int tid = threadIdx.x;
  const int wave = tid >> 6;        // 0..7
  const int lane = tid & 63;
  const int wm = wave >> 1;         // 4x2 wave grid: wm 0..3, wn 0..1
  const int wn = wave & 1;
  const int m0 = blockIdx.y << 8;   // 256-row tiles
  const int n0 = blockIdx.x << 7;   // 128-col tiles

  ushort* const sA = lds;           // + (t&1)<<14 elems
  ushort* const sB = lds + 32768;

  // --- staging: chunk c = round*512 + wave*64 + lane; row = c>>3 (64 rows
  // per round), pos = lane&7, row&7 = lane>>3 (wave- and round-independent).
  const int g8 = lane >> 3;                       // 0..7
  const int qe = ((lane & 7) ^ g8) << 3;          // swizzled k-elem offset [0,64)
  const int rb = (wave << 3) + g8;                // row within 64-row round

  const ushort* Ag = A + (size_t)(m0 + rb) * K + qe;
  const ushort* Bg = B + (size_t)(n0 + rb) * K + qe;
  const size_t rstep = (size_t)64 * K;            // 64 rows per round

  // wave-uniform LDS base offset per round (HW adds lane*16 B)
  const int wbase = wave << 9;                    // wave*512 elems

  // --- fragment reads: row = w?*64 + i*16 + fr; k-chunk p = kk*4 + t4,
  // stored at p ^ (fr&7).
  const int fr = lane & 15;
  const int t4 = lane >> 4;                       // 0..3
  const int pk0 = ((t4 ^ (fr & 7)) << 3);
  const int pk1 = (((4 + t4) ^ (fr & 7)) << 3);

  f32x4 acc[4][4];
#pragma unroll
  for (int i = 0; i < 4; i++)
#pragma unroll
    for (int j = 0; j < 4; j++) acc[i][j] = (f32x4){0.f, 0.f, 0.f, 0.f};

  // ---- prologue: A tile 0 -> buffer 0
#pragma unroll
  for (int r = 0; r < 4; r++)
    gl_lds16(Ag + r * rstep, sA + (r << 12) + wbase);

  const int T = K >> 6;
#pragma unroll 2
  for (int t = 0; t < T; ++t) {
    const int k0 = t << 6;
    ushort* const cur = sA + ((t & 1) << 14);

    // B(t) first (so the counted wait below retires it), then A(t+1).
#pragma unroll
    for (int r = 0; r < 2; r++)
      gl_lds16(Bg + k0 + r * rstep, sB + (r << 12) + wbase);
    if (t + 1 < T) {
      ushort* const nxt = sA + (((t + 1) & 1) << 14);
#pragma unroll
      for (int r = 0; r < 4; r++)
        gl_lds16(Ag + k0 + 64 + r * rstep, nxt + (r << 12) + wbase);
      asm volatile("s_waitcnt vmcnt(4)" ::: "memory");  // A(t)+B(t) landed
    } else {
      asm volatile("s_waitcnt vmcnt(0)" ::: "memory");  // final drain
    }
    __builtin_amdgcn_s_barrier();
    __builtin_amdgcn_sched_barrier(0);   // pin: no ds_read hoists above bar

#pragma unroll
    for (int kk = 0; kk < 2; kk++) {
      const int pk = kk ? pk1 : pk0;
      bf16x8 fa[4], fb[4];
#pragma unroll
      for (int i = 0; i < 4; i++)
        fa[i] = *(const bf16x8*)(cur + (((wm << 6) + (i << 4) + fr) << 6) + pk);
#pragma unroll
      for (int j = 0; j < 4; j++)
        fb[j] = *(const bf16x8*)(sB + (((wn << 6) + (j << 4) + fr) << 6) + pk);

#pragma unroll
      for (int i = 0; i < 4; i++)
#pragma unroll
        for (int j = 0; j < 4; j++)
          acc[i][j] = __builtin_amdgcn_mfma_f32_16x16x32_bf16(
              fa[i], fb[j], acc[i][j], 0, 0, 0);
    }
    __builtin_amdgcn_s_barrier();        // reads of cur/sB done before re-stage
  }

  // Epilogue: C/D layout col = lane&15, row = (lane>>4)*4 + reg. Fuse bias.
  const int row0 = m0 + (wm << 6) + (t4 << 2);
  const int col0 = n0 + (wn << 6) + fr;
#pragma unroll
  for (int j = 0; j < 4; j++) {
    const int col = col0 + (j << 4);
    const float bv = bq[col];
#pragma unroll
    for (int i = 0; i < 4; i++) {
      const int row = row0 + (i << 4);
#pragma unroll
      for (int r = 0; r < 4; r++)
        C[(size_t)(row + r) * N + col] = acc[i][j][r] + bv;
    }
  }
}

extern "C" void kernel_launch(void* const* d_in, const int* in_sizes, int n_in,
                              void* d_out, int out_size, void* d_ws, size_t ws_size,
                              hipStream_t stream) {
  const float* x = (const float*)d_in[0];
  const float* w = (const float*)d_in[1];
  const float* bias = (const float*)d_in[2];
  float* out = (float*)d_out;

  const int out_f = in_sizes[2];                 // 2048
  const int in_f = in_sizes[1] / out_f;          // 2048
  const int m = in_sizes[0] / in_f;              // 8192
  const int k = in_f;

  // workspace layout: Xq bf16 | Wq bf16 | bq fp32
  ushort* Xq = (ushort*)d_ws;
  ushort* Wq = Xq + (size_t)m * k;
  float* bquant = (float*)(Wq + (size_t)out_f * k);

  const int nx4 = in_sizes[0] / 4;
  const int nw4 = in_sizes[1] / 4;
  const int nb4 = in_sizes[2] / 4;
  const int total4 = nx4 + nw4 + nb4;
  posit_quant_all<<<(total4 + 255) / 256, 256, 0, stream>>>(
      x, w, bias, Xq, Wq, bquant, nx4, nw4, nb4);

  dim3 grid(out_f / 128, m / 256);
  posit_gemm<<<grid, 512, 0, stream>>>(Xq, Wq, bquant, out, m, out_f, k);
}

// Round 4
// 189.029 us; speedup vs baseline: 1.1026x; 1.0041x over previous
//
#include <hip/hip_runtime.h>

typedef __attribute__((ext_vector_type(8))) short bf16x8;
typedef __attribute__((ext_vector_type(4))) float f32x4;

// ---------------------------------------------------------------------------
// Posit(8,1) round-to-nearest posit quantization, bit-exact vs jnp reference.
// ---------------------------------------------------------------------------
__device__ __forceinline__ float posit_q(float x) {
  float ax = fabsf(x);
  ax = fmaxf(ax, 0x1p-12f);
  ax = fminf(ax, 0x1p12f);
  int s = (int)(__float_as_uint(ax) >> 23) - 127;   // floor(log2(ax)), exact
  int k = s >> 1;                                   // floor(s/2)
  int rlen = (k >= 0) ? (k + 2) : (1 - k);
  int fbits = 6 - rlen;
  fbits = fbits < 0 ? 0 : fbits;
  float m = ax * __uint_as_float((unsigned)(127 - s) << 23);  // [1,2)
  float fs = (float)(1 << fbits);
  float inv_fs = __uint_as_float((unsigned)(127 - fbits) << 23);
  float mq = rintf(m * fs) * inv_fs;                // round-half-even = jnp.round
  if (mq >= 2.0f) { s += 1; mq = 1.0f; }            // mantissa carry
  float y = mq * __uint_as_float((unsigned)(127 + s) << 23);
  y = fminf(y, 0x1p12f);
  y = copysignf(y, x);
  return (x == 0.0f) ? 0.0f : y;
}

__device__ __forceinline__ ushort4 quant4_bf16(float4 v) {
  ushort4 o;
  o.x = (ushort)(__float_as_uint(posit_q(v.x)) >> 16);
  o.y = (ushort)(__float_as_uint(posit_q(v.y)) >> 16);
  o.z = (ushort)(__float_as_uint(posit_q(v.z)) >> 16);
  o.w = (ushort)(__float_as_uint(posit_q(v.w)) >> 16);
  return o;
}

__global__ void posit_quant_all(const float* __restrict__ x,
                                const float* __restrict__ w,
                                const float* __restrict__ b,
                                ushort* __restrict__ Xq,
                                ushort* __restrict__ Wq,
                                float* __restrict__ bq,
                                int nx4, int nw4, int nb4) {
  int i = blockIdx.x * blockDim.x + threadIdx.x;
  if (i < nx4) {
    ((ushort4*)Xq)[i] = quant4_bf16(((const float4*)x)[i]);
  } else if (i < nx4 + nw4) {
    int j = i - nx4;
    ((ushort4*)Wq)[j] = quant4_bf16(((const float4*)w)[j]);
  } else if (i < nx4 + nw4 + nb4) {
    int j = i - nx4 - nw4;
    float4 v = ((const float4*)b)[j];
    float4 o;
    o.x = posit_q(v.x); o.y = posit_q(v.y);
    o.z = posit_q(v.z); o.w = posit_q(v.w);
    ((float4*)bq)[j] = o;
  }
}

// ---------------------------------------------------------------------------
// R9: 256x256 tile, BK=32, QUAD-buffered LDS (4 x 32 KB = 128 KB), ONE
// s_barrier + ONE counted vmcnt per K-step. 512 thr = 8 waves (2M x 4N),
// 128x64 out/wave. Grid 8x32 = 256 blocks = 1/CU.
//
// Rationale (R5..R8 ingest model): all saturating kernels run at ~19-25 B/cyc
// per CU of global->LDS ingest; time = stagedBytes/CU / ingest. 256x128
// stages 3.1 MB/CU (-> 68 us); 256x256 stages 2.1 MB/CU (-> ~45 us). The
// step shape is R8's proven {stage; counted wait; barrier; compute} - no
// multi-phase lockstep (R6/R7 starved ingest at 10-11 B/cyc).
//
// Pipeline (per-wave FIFO, 4 gl_lds per wave per step):
//   prologue: stage t0->buf0, t1->buf1; vmcnt(4) retires t0; barrier.
//   step t:   stage t+2 -> buf[(t+2)&3]; vmcnt(4) retires t+1 (issued one
//             full step ago); barrier; compute t from buf[t&3] (t retired at
//             step t-1). Never drains to 0 mid-loop (T4). Tail: vmcnt(0).
// WAR with ONE barrier: stage target buf[(t+2)&3]=buf[(t-2)&3] was last read
// during compute(t-2); any wave past bar(t) implies all waves completed
// [stage;wait] of step t, i.e. finished compute(t-1) (and a fortiori t-2).
// Unroll 4 => all buffer offsets compile-time (no dyn-indexed LDS, rule #20).
//
// Swizzle (BK=32): row r has 4 16B-chunks; chunk p stored at slot
// p ^ ((r>>2)&3), pre-applied to the GLOBAL source (LDS dests stay
// lane-linear for global_load_lds). Fragment ds_read_b128: within each
// 16-lane phase group, banks = (fr&1)*16 + (t4^(fr>>2))*4 -> 2 lanes per
// 4-bank span = 2-way aliasing = free (m136).
// ---------------------------------------------------------------------------
__device__ __forceinline__ void gl_lds16(const ushort* g, ushort* l) {
  __builtin_amdgcn_global_load_lds(
      (const __attribute__((address_space(1))) void*)g,
      (__attribute__((address_space(3))) void*)l,
      16, 0, 0);
}

#define BAR() do { __builtin_amdgcn_s_barrier(); \
                   __builtin_amdgcn_sched_barrier(0); } while (0)

__global__ __launch_bounds__(512, 2) void posit_gemm(
    const ushort* __restrict__ A, const ushort* __restrict__ B,
    const float* __restrict__ bq, float* __restrict__ C,
    int M, int N, int K) {
  __shared__ ushort lds[65536];   // 4 buffers x 16384 elems (A 8192 | B 8192)

  const int tid = threadIdx.x;
  const int wave = tid >> 6;        // 0..7
  const int lane = tid & 63;
  const int wm = wave >> 2;         // 0..1 : 128-row slab
  const int wn = wave & 3;          // 0..3 : 64-col slab
  const int m0 = blockIdx.y << 8;
  const int n0 = blockIdx.x << 8;

  // --- staging: instruction q in {0,1} per operand covers rows
  // q*128 + wave*16 + (lane>>2); 4 lanes per row = 4 chunks of 8 elems.
  // Pre-swizzled source chunk = (lane&3) ^ ((row>>2)&3) = (lane&3)^(lane>>4).
  const int srow = (wave << 4) + (lane >> 2);
  const int sk = (((lane & 3) ^ (lane >> 4)) << 3);   // k-elem offset [0,32)
  const ushort* Ag = A + (size_t)(m0 + srow) * K + sk;
  const ushort* Bg = B + (size_t)(n0 + srow) * K + sk;
  const size_t rstep = (size_t)128 * K;               // rows covered per instr
  const int sbase = wave << 9;                        // wave*512 elems

  // stage tile kt (k-offset kt*32) into buffer base Lb
#define STAGE(Lb, kt) do {                                         \
    const ushort* _ag = Ag + ((size_t)(kt) << 5);                  \
    const ushort* _bg = Bg + ((size_t)(kt) << 5);                  \
    gl_lds16(_ag,         (Lb) + sbase);                           \
    gl_lds16(_ag + rstep, (Lb) + 4096 + sbase);                    \
    gl_lds16(_bg,         (Lb) + 8192 + sbase);                    \
    gl_lds16(_bg + rstep, (Lb) + 12288 + sbase);                   \
  } while (0)

  // --- fragment reads: row = slab + i*16 + fr; slot = t4 ^ ((fr>>2)&3).
  const int fr = lane & 15;
  const int t4 = lane >> 4;                           // 0..3
  const int sl = ((t4 ^ (fr >> 2)) << 3);             // swizzled elem offset
  const int arl = (((wm << 7) + fr) << 5) + sl;       // + i*512
  const int brl = (((wn << 6) + fr) << 5) + sl + 8192;// + j*512

  f32x4 acc[8][4];
#pragma unroll
  for (int i = 0; i < 8; i++)
#pragma unroll
    for (int j = 0; j < 4; j++) acc[i][j] = (f32x4){0.f, 0.f, 0.f, 0.f};

#define COMP(Lb) do {                                              \
    bf16x8 fa[8], fb[4];                                           \
    _Pragma("unroll")                                              \
    for (int i = 0; i < 8; i++)                                    \
      fa[i] = *(const bf16x8*)((Lb) + arl + (i << 9));             \
    _Pragma("unroll")                                              \
    for (int j = 0; j < 4; j++)                                    \
      fb[j] = *(const bf16x8*)((Lb) + brl + (j << 9));             \
    _Pragma("unroll")                                              \
    for (int i = 0; i < 8; i++)                                    \
      _Pragma("unroll")                                            \
      for (int j = 0; j < 4; j++)                                  \
        acc[i][j] = __builtin_amdgcn_mfma_f32_16x16x32_bf16(       \
            fa[i], fb[j], acc[i][j], 0, 0, 0);                     \
  } while (0)

  const int T = K >> 5;               // 64 K-steps of 32

  // ---- prologue: t0 -> buf0, t1 -> buf1
  STAGE(lds, 0);
  STAGE(lds + 16384, 1);
  asm volatile("s_waitcnt vmcnt(4)" ::: "memory");    // t0 landed
  BAR();

#pragma unroll 1
  for (int it = 0; it < (T >> 2); ++it) {
    const int t0 = it << 2;
#pragma unroll
    for (int u = 0; u < 4; ++u) {
      const int t = t0 + u;
      ushort* const cb = lds + (u << 14);                 // buf t&3 (static)
      ushort* const nb = lds + (((u + 2) & 3) << 14);     // buf (t+2)&3
      if (t + 2 < T) {
        STAGE(nb, t + 2);
        asm volatile("s_waitcnt vmcnt(4)" ::: "memory");  // t+1 retired
      } else {
        asm volatile("s_waitcnt vmcnt(0)" ::: "memory");  // tail drain
      }
      BAR();
      COMP(cb);
    }
  }

  // Epilogue: C/D layout col = lane&15, row = (lane>>4)*4 + reg. Fuse bias.
  const int row0 = m0 + (wm << 7) + (t4 << 2);
  const int col0 = n0 + (wn << 6) + fr;
#pragma unroll
  for (int j = 0; j < 4; j++) {
    const int col = col0 + (j << 4);
    const float bv = bq[col];
#pragma unroll
    for (int i = 0; i < 8; i++) {
      const int row = row0 + (i << 4);
#pragma unroll
      for (int r = 0; r < 4; r++)
        C[(size_t)(row + r) * N + col] = acc[i][j][r] + bv;
    }
  }
}

extern "C" void kernel_launch(void* const* d_in, const int* in_sizes, int n_in,
                              void* d_out, int out_size, void* d_ws, size_t ws_size,
                              hipStream_t stream) {
  const float* x = (const float*)d_in[0];
  const float* w = (const float*)d_in[1];
  const float* bias = (const float*)d_in[2];
  float* out = (float*)d_out;

  const int out_f = in_sizes[2];                 // 2048
  const int in_f = in_sizes[1] / out_f;          // 2048
  const int m = in_sizes[0] / in_f;              // 8192
  const int k = in_f;

  // workspace layout: Xq bf16 | Wq bf16 | bq fp32
  ushort* Xq = (ushort*)d_ws;
  ushort* Wq = Xq + (size_t)m * k;
  float* bquant = (float*)(Wq + (size_t)out_f * k);

  const int nx4 = in_sizes[0] / 4;
  const int nw4 = in_sizes[1] / 4;
  const int nb4 = in_sizes[2] / 4;
  const int total4 = nx4 + nw4 + nb4;
  posit_quant_all<<<(total4 + 255) / 256, 256, 0, stream>>>(
      x, w, bias, Xq, Wq, bquant, nx4, nw4, nb4);

  dim3 grid(out_f / 256, m / 256);
  posit_gemm<<<grid, 512, 0, stream>>>(Xq, Wq, bquant, out, m, out_f, k);
}

// Round 5
// 186.459 us; speedup vs baseline: 1.1178x; 1.0138x over previous
//
#include <hip/hip_runtime.h>

typedef __attribute__((ext_vector_type(8))) short bf16x8;
typedef __attribute__((ext_vector_type(4))) float f32x4;

// ---------------------------------------------------------------------------
// Posit(8,1) round-to-nearest posit quantization, bit-exact vs jnp reference.
// ---------------------------------------------------------------------------
__device__ __forceinline__ float posit_q(float x) {
  float ax = fabsf(x);
  ax = fmaxf(ax, 0x1p-12f);
  ax = fminf(ax, 0x1p12f);
  int s = (int)(__float_as_uint(ax) >> 23) - 127;   // floor(log2(ax)), exact
  int k = s >> 1;                                   // floor(s/2)
  int rlen = (k >= 0) ? (k + 2) : (1 - k);
  int fbits = 6 - rlen;
  fbits = fbits < 0 ? 0 : fbits;
  float m = ax * __uint_as_float((unsigned)(127 - s) << 23);  // [1,2)
  float fs = (float)(1 << fbits);
  float inv_fs = __uint_as_float((unsigned)(127 - fbits) << 23);
  float mq = rintf(m * fs) * inv_fs;                // round-half-even = jnp.round
  if (mq >= 2.0f) { s += 1; mq = 1.0f; }            // mantissa carry
  float y = mq * __uint_as_float((unsigned)(127 + s) << 23);
  y = fminf(y, 0x1p12f);
  y = copysignf(y, x);
  return (x == 0.0f) ? 0.0f : y;
}

__device__ __forceinline__ ushort4 quant4_bf16(float4 v) {
  ushort4 o;
  o.x = (ushort)(__float_as_uint(posit_q(v.x)) >> 16);
  o.y = (ushort)(__float_as_uint(posit_q(v.y)) >> 16);
  o.z = (ushort)(__float_as_uint(posit_q(v.z)) >> 16);
  o.w = (ushort)(__float_as_uint(posit_q(v.w)) >> 16);
  return o;
}

__global__ void posit_quant_all(const float* __restrict__ x,
                                const float* __restrict__ w,
                                const float* __restrict__ b,
                                ushort* __restrict__ Xq,
                                ushort* __restrict__ Wq,
                                float* __restrict__ bq,
                                int nx4, int nw4, int nb4) {
  int i = blockIdx.x * blockDim.x + threadIdx.x;
  if (i < nx4) {
    ((ushort4*)Xq)[i] = quant4_bf16(((const float4*)x)[i]);
  } else if (i < nx4 + nw4) {
    int j = i - nx4;
    ((ushort4*)Wq)[j] = quant4_bf16(((const float4*)w)[j]);
  } else if (i < nx4 + nw4 + nb4) {
    int j = i - nx4 - nw4;
    float4 v = ((const float4*)b)[j];
    float4 o;
    o.x = posit_q(v.x); o.y = posit_q(v.y);
    o.z = posit_q(v.z); o.w = posit_q(v.w);
    ((float4*)bq)[j] = o;
  }
}

// ---------------------------------------------------------------------------
// R10 = R9 with the two counter-diagnosed defects fixed:
//  (1) conflict-free BK=32 swizzle: 6.29M conflict-cyc in R9 came from slot =
//      t4^((row>>2)&3): an 8-lane HW phase (consecutive fr, 64B rows) hit only
//      2 of 8 (parity,slot) bank groups. Fix: slot = chunk ^ ((row>>1)&3) ->
//      8 consecutive fr cover all 8 groups exactly once. All fragment row
//      offsets (i*16, wm*128, wn*64) are ==0 mod 4 after >>1, so each lane's
//      swizzle term is uniform across its 12 reads.
//  (2) ingest depth: R9 ran 12.1 B/cyc (2.1MB/173k) with one tile (32KB/CU)
//      in flight -> Little's-law-capped. R10 keeps THREE tiles in flight:
//      5 buffers x 32KB = 160 KiB LDS (AITER uses 160KB/WG on gfx950);
//      step t: STAGE(t+3); vmcnt(8); bar; COMP(t). Post-wait outstanding =
//      {t+2,t+3} = 64KB/CU across the barrier; tile t landed one full step
//      early. WAR: stage(t+3) -> buf[(t-2)%5], last read in COMP(t-2),
//      separated from the overwrite by bar(t-1). Tail: vmcnt(4) at T-3,
//      vmcnt(0) at T-2; never drains mid-loop (T4).
// Geometry unchanged: 256x256, BK=32, 512 thr = 8 waves (2Mx4N), 128x64
// out/wave, grid 8x32 = 256 = 1 block/CU. Staged bytes 2.1 MB/CU (vs
// R5/R8's 3.1) -> at ~18 B/cyc ingest => ~50 us.
// ---------------------------------------------------------------------------
__device__ __forceinline__ void gl_lds16(const ushort* g, ushort* l) {
  __builtin_amdgcn_global_load_lds(
      (const __attribute__((address_space(1))) void*)g,
      (__attribute__((address_space(3))) void*)l,
      16, 0, 0);
}

#define BAR() do { __builtin_amdgcn_s_barrier(); \
                   __builtin_amdgcn_sched_barrier(0); } while (0)

__global__ __launch_bounds__(512, 2) void posit_gemm(
    const ushort* __restrict__ A, const ushort* __restrict__ B,
    const float* __restrict__ bq, float* __restrict__ C,
    int M, int N, int K) {
  __shared__ ushort lds[81920];   // 160 KiB: 5 buffers x 16384 elems (A|B 8192 each)

  const int tid = threadIdx.x;
  const int wave = tid >> 6;        // 0..7
  const int lane = tid & 63;
  const int wm = wave >> 2;         // 0..1 : 128-row slab
  const int wn = wave & 3;          // 0..3 : 64-col slab
  const int m0 = blockIdx.y << 8;
  const int n0 = blockIdx.x << 8;

  // --- staging: instr q in {0,1} per operand covers rows q*128+wave*16+(lane>>2);
  // 4 lanes per row. Stored slot of chunk p, row r = p ^ ((r>>1)&3); LDS dest is
  // lane-linear, so fetch source chunk (lane&3) ^ ((srow>>1)&3); srow>>1 =
  // wave*8 + (lane>>3) -> &3 = (lane>>3)&3 (wave term ==0 mod 4).
  const int srow = (wave << 4) + (lane >> 2);
  const int sk = (((lane & 3) ^ ((lane >> 3) & 3)) << 3);  // k-elem offset [0,32)
  const ushort* Ag = A + (size_t)(m0 + srow) * K + sk;
  const ushort* Bg = B + (size_t)(n0 + srow) * K + sk;
  const size_t rstep = (size_t)128 * K;               // rows covered per instr
  const int sbase = wave << 9;                        // wave*512 elems

#define STAGE(Lb, kt) do {                                         \
    const ushort* _ag = Ag + ((size_t)(kt) << 5);                  \
    const ushort* _bg = Bg + ((size_t)(kt) << 5);                  \
    gl_lds16(_ag,         (Lb) + sbase);                           \
    gl_lds16(_ag + rstep, (Lb) + 4096 + sbase);                    \
    gl_lds16(_bg,         (Lb) + 8192 + sbase);                    \
    gl_lds16(_bg + rstep, (Lb) + 12288 + sbase);                   \
  } while (0)

  // --- fragment reads: row = slab + i*16 + fr; needed chunk = t4; read slot =
  // t4 ^ ((fr>>1)&3)  (slab/i terms ==0 mod 4 after >>1).
  const int fr = lane & 15;
  const int t4 = lane >> 4;                           // 0..3
  const int sl = ((t4 ^ ((fr >> 1) & 3)) << 3);       // swizzled elem offset
  const int arl = (((wm << 7) + fr) << 5) + sl;       // + i*512
  const int brl = (((wn << 6) + fr) << 5) + sl + 8192;// + j*512

  f32x4 acc[8][4];
#pragma unroll
  for (int i = 0; i < 8; i++)
#pragma unroll
    for (int j = 0; j < 4; j++) acc[i][j] = (f32x4){0.f, 0.f, 0.f, 0.f};

#define COMP(Lb) do {                                              \
    bf16x8 fa[8], fb[4];                                           \
    _Pragma("unroll")                                              \
    for (int i = 0; i < 8; i++)                                    \
      fa[i] = *(const bf16x8*)((Lb) + arl + (i << 9));             \
    _Pragma("unroll")                                              \
    for (int j = 0; j < 4; j++)                                    \
      fb[j] = *(const bf16x8*)((Lb) + brl + (j << 9));             \
    _Pragma("unroll")                                              \
    for (int i = 0; i < 8; i++)                                    \
      _Pragma("unroll")                                            \
      for (int j = 0; j < 4; j++)                                  \
        acc[i][j] = __builtin_amdgcn_mfma_f32_16x16x32_bf16(       \
            fa[i], fb[j], acc[i][j], 0, 0, 0);                     \
  } while (0)

  const int T = K >> 5;               // 64 K-steps of 32

  // ---- prologue: t0->buf0, t1->buf1, t2->buf2; retire t0; barrier.
  STAGE(lds,         0);
  STAGE(lds + 16384, 1);
  STAGE(lds + 32768, 2);
  asm volatile("s_waitcnt vmcnt(8)" ::: "memory");
  BAR();

  int cbi = 0;                        // t   mod 5 (compute buffer)
  int sbi = 3;                        // t+3 mod 5 (stage target)
#pragma unroll 1
  for (int t = 0; t < T - 3; ++t) {
    ushort* const cb = lds + (cbi << 14);
    ushort* const sb = lds + (sbi << 14);
    STAGE(sb, t + 3);
    asm volatile("s_waitcnt vmcnt(8)" ::: "memory");  // t+1 retired; {t+2,t+3} in flight
    BAR();
    COMP(cb);
    cbi = (cbi == 4) ? 0 : cbi + 1;
    sbi = (sbi == 4) ? 0 : sbi + 1;
  }
  // ---- tail: t = T-3, T-2, T-1 (no more staging)
#pragma unroll 1
  for (int t = T - 3; t < T; ++t) {
    ushort* const cb = lds + (cbi << 14);
    if (t == T - 3)      asm volatile("s_waitcnt vmcnt(4)" ::: "memory");
    else if (t == T - 2) asm volatile("s_waitcnt vmcnt(0)" ::: "memory");
    BAR();
    COMP(cb);
    cbi = (cbi == 4) ? 0 : cbi + 1;
  }

  // Epilogue: C/D layout col = lane&15, row = (lane>>4)*4 + reg. Fuse bias.
  const int row0 = m0 + (wm << 7) + (t4 << 2);
  const int col0 = n0 + (wn << 6) + fr;
#pragma unroll
  for (int j = 0; j < 4; j++) {
    const int col = col0 + (j << 4);
    const float bv = bq[col];
#pragma unroll
    for (int i = 0; i < 8; i++) {
      const int row = row0 + (i << 4);
#pragma unroll
      for (int r = 0; r < 4; r++)
        C[(size_t)(row + r) * N + col] = acc[i][j][r] + bv;
    }
  }
}

extern "C" void kernel_launch(void* const* d_in, const int* in_sizes, int n_in,
                              void* d_out, int out_size, void* d_ws, size_t ws_size,
                              hipStream_t stream) {
  const float* x = (const float*)d_in[0];
  const float* w = (const float*)d_in[1];
  const float* bias = (const float*)d_in[2];
  float* out = (float*)d_out;

  const int out_f = in_sizes[2];                 // 2048
  const int in_f = in_sizes[1] / out_f;          // 2048
  const int m = in_sizes[0] / in_f;              // 8192
  const int k = in_f;

  // workspace layout: Xq bf16 | Wq bf16 | bq fp32
  ushort* Xq = (ushort*)d_ws;
  ushort* Wq = Xq + (size_t)m * k;
  float* bquant = (float*)(Wq + (size_t)out_f * k);

  const int nx4 = in_sizes[0] / 4;
  const int nw4 = in_sizes[1] / 4;
  const int nb4 = in_sizes[2] / 4;
  const int total4 = nx4 + nw4 + nb4;
  posit_quant_all<<<(total4 + 255) / 256, 256, 0, stream>>>(
      x, w, bias, Xq, Wq, bquant, nx4, nw4, nb4);

  dim3 grid(out_f / 256, m / 256);
  posit_gemm<<<grid, 512, 0, stream>>>(Xq, Wq, bquant, out, m, out_f, k);
}